// Round 5
// baseline (320.986 us; speedup 1.0000x reference)
//
#include <hip/hip_runtime.h>
#include <hip/hip_bf16.h>
#include <stdint.h>

// ---------- types ----------
typedef __attribute__((ext_vector_type(8))) short short8;   // 8 bf16 in 4 VGPRs
typedef __attribute__((ext_vector_type(4))) float floatx4;  // MFMA accumulator

#define GPTR(p) (const __attribute__((address_space(1))) void*)(p)
#define LPTR(p) (__attribute__((address_space(3))) void*)(p)

__device__ __forceinline__ ushort f2bf(float f) {
    union { float f; uint32_t u; } v; v.f = f;
    uint32_t u = v.u;
    uint32_t r = (u + 0x7FFFu + ((u >> 16) & 1u)) >> 16;   // RNE
    return (ushort)r;
}
__device__ __forceinline__ float bf2f(ushort b) {
    union { uint32_t u; float f; } v; v.u = ((uint32_t)b) << 16;
    return v.f;
}

// ---------- kernel 1: query-row extract (computes t from mask inline) ----------
__global__ void qrow_kernel(const float* __restrict__ x, const int* __restrict__ mask,
                            ushort* __restrict__ xq) {
    __shared__ int t_sh;
    int bw = blockIdx.x, tid = threadIdx.x;
    if (tid < 32) {
        int s = mask[bw * 32 + tid];
        #pragma unroll
        for (int off = 16; off; off >>= 1) s += __shfl_xor(s, off);
        if (tid == 0) t_sh = s - 1;
    }
    __syncthreads();
    int t = t_sh;
    const float4* src = (const float4*)(x + ((size_t)bw * 32 + t) * 1024);
    float4 v = src[tid];
    ushort4 o;
    o.x = f2bf(v.x); o.y = f2bf(v.y); o.z = f2bf(v.z); o.w = f2bf(v.w);
    ((ushort4*)(xq + (size_t)bw * 1024))[tid] = o;
}

// ---------- kernel 2: weight prep: WqT, WvT, WpT transposes + Wk cast ----------
__global__ void wcvt_kernel(const float* __restrict__ attn_w, const float* __restrict__ proj_w,
                            ushort* __restrict__ wqT, ushort* __restrict__ wk,
                            ushort* __restrict__ wvT, ushort* __restrict__ wpT) {
    __shared__ float tile[32][33];
    int bx = blockIdx.x;                 // 0..127
    int r0 = blockIdx.y * 32;
    int tx = threadIdx.x, ty = threadIdx.y;
    if (bx >= 96) {                      // cast path: wk[r][c] = attn_w[r][1024+c]
        int c0 = (bx - 96) * 32;
        for (int i = ty; i < 32; i += 8)
            wk[(size_t)(r0 + i) * 1024 + c0 + tx] =
                f2bf(attn_w[(size_t)(r0 + i) * 3072 + 1024 + c0 + tx]);
        return;
    }
    const float* src; ushort* dst; int N, csrc0, c0;
    if (bx < 32)      { src = attn_w; dst = wqT; N = 3072; c0 = bx * 32;        csrc0 = c0; }
    else if (bx < 64) { src = attn_w; dst = wvT; N = 3072; c0 = (bx - 32) * 32; csrc0 = 2048 + c0; }
    else              { src = proj_w; dst = wpT; N = 1024; c0 = (bx - 64) * 32; csrc0 = c0; }
    for (int i = ty; i < 32; i += 8)
        tile[i][tx] = src[(size_t)(r0 + i) * N + csrc0 + tx];
    __syncthreads();
    for (int i = ty; i < 32; i += 8)
        dst[(size_t)(c0 + i) * 1024 + r0 + tx] = f2bf(tile[tx][i]);
}

// ---------- kernel 3: split-K 64-tile GEMM, M=N=1024, lda=ldb=1024 ----------
// z = K-slice (4 slices of 256); partials to f32 planes Cpart[z][1024][1024].
__global__ __launch_bounds__(256)
void gemm64sk_kernel(const ushort* __restrict__ A, const ushort* __restrict__ Bt,
                     float* __restrict__ Cpart) {
    __shared__ ushort As[64 * 32];
    __shared__ ushort Bs[64 * 32];

    const int bm = blockIdx.x, bn = blockIdx.y, z = blockIdx.z;
    const int kofs = z * 256;

    const int tid  = threadIdx.x;
    const int wave = tid >> 6;
    const int lane = tid & 63;
    const int wm = wave & 1, wn = wave >> 1;
    const int quad = lane >> 4, l15 = lane & 15;

    floatx4 acc[2][2] = {};

    const int srow = wave * 16 + (lane >> 2);
    const int kcol = (lane & 3) * 8;

    for (int kt = 0; kt < 256; kt += 32) {
        const ushort* gA = A  + (size_t)(bm * 64 + srow) * 1024 + kofs + kt + kcol;
        const ushort* gB = Bt + (size_t)(bn * 64 + srow) * 1024 + kofs + kt + kcol;
        ushort* lA = As + (wave * 16) * 32;
        ushort* lB = Bs + (wave * 16) * 32;
        __builtin_amdgcn_global_load_lds(GPTR(gA), LPTR(lA), 16, 0, 0);
        __builtin_amdgcn_global_load_lds(GPTR(gB), LPTR(lB), 16, 0, 0);
        __syncthreads();

        short8 af[2], bf[2];
        #pragma unroll
        for (int i = 0; i < 2; ++i)
            af[i] = *(const short8*)&As[(wm * 32 + i * 16 + l15) * 32 + quad * 8];
        #pragma unroll
        for (int j = 0; j < 2; ++j)
            bf[j] = *(const short8*)&Bs[(wn * 32 + j * 16 + l15) * 32 + quad * 8];
        #pragma unroll
        for (int i = 0; i < 2; ++i)
            #pragma unroll
            for (int j = 0; j < 2; ++j)
                acc[i][j] = __builtin_amdgcn_mfma_f32_16x16x32_bf16(af[i], bf[j], acc[i][j], 0, 0, 0);
        __syncthreads();
    }

    #pragma unroll
    for (int i = 0; i < 2; ++i) {
        #pragma unroll
        for (int j = 0; j < 2; ++j) {
            int r0 = bm * 64 + wm * 32 + i * 16 + quad * 4;
            int c  = bn * 64 + wn * 32 + j * 16 + l15;
            #pragma unroll
            for (int r = 0; r < 4; ++r)
                Cpart[(size_t)z * 1048576 + (size_t)(r0 + r) * 1024 + c] = acc[i][j][r];
        }
    }
}

// ---------- kernel 3b: combine 4 f32 partial planes ----------
template <bool OUT_BF16>
__global__ void combine4_kernel(const float* __restrict__ P, void* __restrict__ C) {
    int i = blockIdx.x * 256 + threadIdx.x;     // 262144 threads, one float4 each
    const float4* p = (const float4*)P;
    float4 a = p[i], b = p[i + 262144], c = p[i + 524288], d = p[i + 786432];
    float4 s;
    s.x = a.x + b.x + c.x + d.x;
    s.y = a.y + b.y + c.y + d.y;
    s.z = a.z + b.z + c.z + d.z;
    s.w = a.w + b.w + c.w + d.w;
    if (OUT_BF16) {
        ushort4 o;
        o.x = f2bf(s.x); o.y = f2bf(s.y); o.z = f2bf(s.z); o.w = f2bf(s.w);
        ((ushort4*)C)[i] = o;
    } else {
        ((float4*)C)[i] = s;
    }
}

// ---------- kernel 4: 128-tile GEMM (batched/strided) for U ----------
template <bool OUT_BF16>
__global__ __launch_bounds__(256)
void gemm128_kernel(const ushort* __restrict__ A, int lda, long sA,
                    const ushort* __restrict__ Bt, int ldb, long sB,
                    void* __restrict__ C, int ldc, long sC, int K) {
    __shared__ ushort As[128 * 32];
    __shared__ ushort Bs[128 * 32];

    const int bm = blockIdx.x, bn = blockIdx.y, z = blockIdx.z;
    A  += (size_t)z * sA;
    Bt += (size_t)z * sB;

    const int tid  = threadIdx.x;
    const int wave = tid >> 6;
    const int lane = tid & 63;
    const int wm = wave & 1, wn = wave >> 1;
    const int quad = lane >> 4, l15 = lane & 15;

    floatx4 acc[4][4] = {};

    const int arow = bm * 128 + wave * 16 + (lane >> 2);
    const int brow = bn * 128 + wave * 16 + (lane >> 2);
    const int kcol = (lane & 3) * 8;

    for (int kt = 0; kt < K; kt += 32) {
        #pragma unroll
        for (int iss = 0; iss < 2; ++iss) {
            const ushort* gA = A  + (size_t)(arow + iss * 64) * lda + kt + kcol;
            const ushort* gB = Bt + (size_t)(brow + iss * 64) * ldb + kt + kcol;
            ushort* lA = As + (iss * 64 + wave * 16) * 32;
            ushort* lB = Bs + (iss * 64 + wave * 16) * 32;
            __builtin_amdgcn_global_load_lds(GPTR(gA), LPTR(lA), 16, 0, 0);
            __builtin_amdgcn_global_load_lds(GPTR(gB), LPTR(lB), 16, 0, 0);
        }
        __syncthreads();

        short8 af[4], bf[4];
        #pragma unroll
        for (int i = 0; i < 4; ++i)
            af[i] = *(const short8*)&As[(wm * 64 + i * 16 + l15) * 32 + quad * 8];
        #pragma unroll
        for (int j = 0; j < 4; ++j)
            bf[j] = *(const short8*)&Bs[(wn * 64 + j * 16 + l15) * 32 + quad * 8];
        #pragma unroll
        for (int i = 0; i < 4; ++i)
            #pragma unroll
            for (int j = 0; j < 4; ++j)
                acc[i][j] = __builtin_amdgcn_mfma_f32_16x16x32_bf16(af[i], bf[j], acc[i][j], 0, 0, 0);
        __syncthreads();
    }

    #pragma unroll
    for (int i = 0; i < 4; ++i) {
        #pragma unroll
        for (int j = 0; j < 4; ++j) {
            int r0 = bm * 128 + wm * 64 + i * 16 + quad * 4;
            int c  = bn * 128 + wn * 64 + j * 16 + l15;
            #pragma unroll
            for (int r = 0; r < 4; ++r) {
                float v = acc[i][j][r];
                size_t idx = (size_t)z * sC + (size_t)(r0 + r) * ldc + c;
                if (OUT_BF16) ((ushort*)C)[idx] = f2bf(v);
                else          ((float*) C)[idx] = v;
            }
        }
    }
}

// ---------- kernel 4b: 64-tile GEMM (batched/strided), optional pos-add ----------
template <bool OUT_BF16, bool ADD_POS>
__global__ __launch_bounds__(256)
void gemm64_kernel(const ushort* __restrict__ A, int lda, long sA,
                   const ushort* __restrict__ Bt, int ldb, long sB,
                   void* __restrict__ C, int ldc, int cColPerZ, int K,
                   const float* __restrict__ pos) {
    __shared__ ushort As[64 * 32];
    __shared__ ushort Bs[64 * 32];

    const int bm = blockIdx.x, bn = blockIdx.y, z = blockIdx.z;
    A  += (size_t)z * sA;
    Bt += (size_t)z * sB;

    const int tid  = threadIdx.x;
    const int wave = tid >> 6;
    const int lane = tid & 63;
    const int wm = wave & 1, wn = wave >> 1;
    const int quad = lane >> 4, l15 = lane & 15;

    floatx4 acc[2][2] = {};

    const int srow = wave * 16 + (lane >> 2);
    const int kcol = (lane & 3) * 8;

    for (int kt = 0; kt < K; kt += 32) {
        const ushort* gA = A  + (size_t)(bm * 64 + srow) * lda + kt + kcol;
        const ushort* gB = Bt + (size_t)(bn * 64 + srow) * ldb + kt + kcol;
        ushort* lA = As + (wave * 16) * 32;
        ushort* lB = Bs + (wave * 16) * 32;
        __builtin_amdgcn_global_load_lds(GPTR(gA), LPTR(lA), 16, 0, 0);
        __builtin_amdgcn_global_load_lds(GPTR(gB), LPTR(lB), 16, 0, 0);
        __syncthreads();

        short8 af[2], bf[2];
        #pragma unroll
        for (int i = 0; i < 2; ++i)
            af[i] = *(const short8*)&As[(wm * 32 + i * 16 + l15) * 32 + quad * 8];
        #pragma unroll
        for (int j = 0; j < 2; ++j)
            bf[j] = *(const short8*)&Bs[(wn * 32 + j * 16 + l15) * 32 + quad * 8];
        #pragma unroll
        for (int i = 0; i < 2; ++i)
            #pragma unroll
            for (int j = 0; j < 2; ++j)
                acc[i][j] = __builtin_amdgcn_mfma_f32_16x16x32_bf16(af[i], bf[j], acc[i][j], 0, 0, 0);
        __syncthreads();
    }

    #pragma unroll
    for (int i = 0; i < 2; ++i) {
        #pragma unroll
        for (int j = 0; j < 2; ++j) {
            int r0 = bm * 64 + wm * 32 + i * 16 + quad * 4;
            int cc = z * cColPerZ + bn * 64 + wn * 32 + j * 16 + l15;
            #pragma unroll
            for (int r = 0; r < 4; ++r) {
                float v = acc[i][j][r];
                if (ADD_POS) v += pos[(size_t)((r0 + r) & 255) * 1024 + cc];
                size_t idx = (size_t)(r0 + r) * ldc + cc;
                if (OUT_BF16) ((ushort*)C)[idx] = f2bf(v);
                else          ((float*) C)[idx] = v;
            }
        }
    }
}

// ---------- kernel 5: fused scores -> softmax -> Z, one block per window ----------
// Reads x fp32 directly (cvt during staging); U,Z in [bw][h][e] layout.
__global__ __launch_bounds__(256)
void attn2_kernel(const float* __restrict__ x, const int* __restrict__ mask,
                  const ushort* __restrict__ U, ushort* __restrict__ Z) {
    __shared__ ushort Xs[32 * 1032];   // X rows bf16, padded stride
    __shared__ ushort Us[16 * 1032];   // u^h rows, padded
    __shared__ float  Ss[16 * 33];     // raw scores [h][j]
    __shared__ float  Ps[32 * 16];     // normalized probs [j][h]
    __shared__ int    t_sh;

    const int bw = blockIdx.x;
    const int tid = threadIdx.x;
    const int wave = tid >> 6, lane = tid & 63;
    const int quad = lane >> 4, l15 = lane & 15;

    if (tid < 32) {
        int s = mask[bw * 32 + tid];
        #pragma unroll
        for (int off = 16; off; off >>= 1) s += __shfl_xor(s, off);
        if (tid == 0) t_sh = s - 1;
    }
    __syncthreads();
    const int t = t_sh;

    // stage X rows 0..t (fp32 -> bf16) and U row (contiguous 32 KB)
    const float4* xsrc = (const float4*)(x + (size_t)bw * 32 * 1024);
    int n4 = (t + 1) * 256;
    for (int i = tid; i < n4; i += 256) {
        float4 v = xsrc[i];
        int j = i >> 8, c4 = i & 255;
        ushort4 o; o.x = f2bf(v.x); o.y = f2bf(v.y); o.z = f2bf(v.z); o.w = f2bf(v.w);
        *(ushort4*)&Xs[j * 1032 + c4 * 4] = o;
    }
    const ushort* ubase = U + (size_t)bw * 16384;
    for (int i = tid; i < 16 * 128; i += 256) {
        int h = i >> 7, c = i & 127;
        *(short8*)&Us[h * 1032 + c * 8] = *(const short8*)&ubase[i * 8];
    }
    __syncthreads();

    // S = X(32x1024) @ U^T(16x1024): waves 0,1 each do one 16-row m-tile
    if (wave < 2) {
        floatx4 acc = {0.f, 0.f, 0.f, 0.f};
        int arow = wave * 16 + l15;
        for (int kt = 0; kt < 1024; kt += 32) {
            short8 a = *(const short8*)&Xs[arow * 1032 + kt + quad * 8];
            short8 b = *(const short8*)&Us[l15  * 1032 + kt + quad * 8];
            acc = __builtin_amdgcn_mfma_f32_16x16x32_bf16(a, b, acc, 0, 0, 0);
        }
        #pragma unroll
        for (int r = 0; r < 4; ++r)
            Ss[l15 * 33 + wave * 16 + quad * 4 + r] = acc[r] * 0.125f;
    }
    __syncthreads();

    // softmax per head (wave 0): h = l15, quad owns j = quad*8..quad*8+7
    if (wave == 0) {
        float s[8]; float mx = -1e30f;
        #pragma unroll
        for (int r = 0; r < 8; ++r) {
            int j = quad * 8 + r;
            float v = Ss[l15 * 33 + j];
            v = (j <= t) ? v : -1e30f;
            s[r] = v; mx = fmaxf(mx, v);
        }
        mx = fmaxf(mx, __shfl_xor(mx, 16));
        mx = fmaxf(mx, __shfl_xor(mx, 32));
        float l = 0.f;
        #pragma unroll
        for (int r = 0; r < 8; ++r) { s[r] = __expf(s[r] - mx); l += s[r]; }
        l += __shfl_xor(l, 16);
        l += __shfl_xor(l, 32);
        float inv = 1.f / l;
        #pragma unroll
        for (int r = 0; r < 8; ++r)
            Ps[(quad * 8 + r) * 16 + l15] = s[r] * inv;
    }
    __syncthreads();

    // Z[h][e] = sum_j P[j][h] * X[j][e]; thread owns 4 consecutive e
    float z[16][4];
    #pragma unroll
    for (int h = 0; h < 16; ++h)
        #pragma unroll
        for (int c = 0; c < 4; ++c) z[h][c] = 0.f;
    const int e0 = tid * 4;
    for (int j = 0; j <= t; ++j) {
        float4 p0 = *(const float4*)&Ps[j * 16 + 0];
        float4 p1 = *(const float4*)&Ps[j * 16 + 4];
        float4 p2 = *(const float4*)&Ps[j * 16 + 8];
        float4 p3 = *(const float4*)&Ps[j * 16 + 12];
        float pr[16] = {p0.x, p0.y, p0.z, p0.w, p1.x, p1.y, p1.z, p1.w,
                        p2.x, p2.y, p2.z, p2.w, p3.x, p3.y, p3.z, p3.w};
        ushort4 xv = *(const ushort4*)&Xs[j * 1032 + e0];
        float xf[4] = {bf2f(xv.x), bf2f(xv.y), bf2f(xv.z), bf2f(xv.w)};
        #pragma unroll
        for (int h = 0; h < 16; ++h)
            #pragma unroll
            for (int c = 0; c < 4; ++c)
                z[h][c] += pr[h] * xf[c];
    }
    #pragma unroll
    for (int h = 0; h < 16; ++h) {
        ushort4 o;
        o.x = f2bf(z[h][0]); o.y = f2bf(z[h][1]);
        o.z = f2bf(z[h][2]); o.w = f2bf(z[h][3]);
        *(ushort4*)&Z[(size_t)bw * 16384 + h * 1024 + e0] = o;
    }
}

// ---------- launch ----------
extern "C" void kernel_launch(void* const* d_in, const int* in_sizes, int n_in,
                              void* d_out, int out_size, void* d_ws, size_t ws_size,
                              hipStream_t stream) {
    const float* x        = (const float*)d_in[0];   // (4,256,32,1024)
    const int*   mask     = (const int*)  d_in[1];   // (4,256,32)
    const float* pos_emb  = (const float*)d_in[2];   // (256,1024)
    const float* attn_w   = (const float*)d_in[3];   // (1024,3072)
    const float* proj_w   = (const float*)d_in[4];   // (1024,1024)
    float*       out      = (float*)d_out;           // (1024,1024)

    const long MB2 = 1048576;

    char* ws = (char*)d_ws;
    size_t off = 0;
    ushort* U_bf  = (ushort*)(ws + off); off += (size_t)16 * MB2 * 2;    // 32 MiB  U[bw][h][e]
    ushort* Z_bf  = (ushort*)(ws + off); off += (size_t)16 * MB2 * 2;    // 32 MiB  Z[bw][h][e]
    float*  qpart = (float*) (ws + off); off += (size_t)4 * MB2 * 4;     // 16 MiB  split-K partials
    float*  opart = (float*) (ws + off); off += (size_t)4 * MB2 * 4;     // 16 MiB
    ushort* wqT   = (ushort*)(ws + off); off += MB2 * 2;
    ushort* wk    = (ushort*)(ws + off); off += MB2 * 2;
    ushort* wvT   = (ushort*)(ws + off); off += MB2 * 2;
    ushort* wpT   = (ushort*)(ws + off); off += MB2 * 2;
    ushort* xq_bf = (ushort*)(ws + off); off += MB2 * 2;
    ushort* q_bf  = (ushort*)(ws + off); off += MB2 * 2;
    ushort* y_bf  = (ushort*)(ws + off); off += MB2 * 2;

    // 1. query rows (t computed inline from mask)
    qrow_kernel<<<1024, 256, 0, stream>>>(x, mask, xq_bf);

    // 2. weight prep
    wcvt_kernel<<<dim3(128, 32), dim3(32, 8), 0, stream>>>(attn_w, proj_w, wqT, wk, wvT, wpT);

    // 3. Q = Xq @ Wq  (1024^3) via split-K=4, then combine -> bf16
    gemm64sk_kernel<<<dim3(16, 16, 4), 256, 0, stream>>>(xq_bf, wqT, qpart);
    combine4_kernel<true><<<1024, 256, 0, stream>>>(qpart, (void*)q_bf);

    // 4. U[bw][h][e] = Q^h @ (Wk^h)^T  — batched 16 x (1024x1024x64)
    gemm128_kernel<true><<<dim3(8, 8, 16), 256, 0, stream>>>(
        q_bf, 1024, 64, wk, 1024, 64, (void*)U_bf, 16384, 1024, 64);

    // 5. fused scores -> softmax -> Z per window (reads x fp32 directly)
    attn2_kernel<<<1024, 256, 0, stream>>>(x, mask, U_bf, Z_bf);

    // 6. y = Z^h @ Wv^h + pos  — batched 16 x (1024x64x1024), bf16 out
    gemm64_kernel<true, true><<<dim3(16, 1, 16), 256, 0, stream>>>(
        Z_bf, 16384, 1024, wvT, 1024, 65536, (void*)y_bf, 1024, 64, 1024, pos_emb);

    // 7. out = y @ Wproj  (1024^3) via split-K=4, then combine -> f32
    gemm64sk_kernel<<<dim3(16, 16, 4), 256, 0, stream>>>(y_bf, wpT, opart);
    combine4_kernel<false><<<1024, 256, 0, stream>>>(opart, (void*)out);
}

// Round 6
// 280.534 us; speedup vs baseline: 1.1442x; 1.1442x over previous
//
#include <hip/hip_runtime.h>
#include <hip/hip_bf16.h>
#include <stdint.h>

// ---------- types ----------
typedef __attribute__((ext_vector_type(8))) short short8;   // 8 bf16 in 4 VGPRs
typedef __attribute__((ext_vector_type(4))) float floatx4;  // MFMA accumulator

#define GPTR(p) (const __attribute__((address_space(1))) void*)(p)
#define LPTR(p) (__attribute__((address_space(3))) void*)(p)

__device__ __forceinline__ ushort f2bf(float f) {
    union { float f; uint32_t u; } v; v.f = f;
    uint32_t u = v.u;
    uint32_t r = (u + 0x7FFFu + ((u >> 16) & 1u)) >> 16;   // RNE
    return (ushort)r;
}
__device__ __forceinline__ float bf2f(ushort b) {
    union { uint32_t u; float f; } v; v.u = ((uint32_t)b) << 16;
    return v.f;
}

// ---------- kernel 1: fused weight prep + query-row extract ----------
// grid (160, 32): bx<128 -> weight transpose/cast tile (bx, by);
//                 bx>=128 -> query row for window bw=(bx-128)*32+by.
__global__ void prep_kernel(const float* __restrict__ attn_w, const float* __restrict__ proj_w,
                            const float* __restrict__ x, const int* __restrict__ mask,
                            ushort* __restrict__ wqT, ushort* __restrict__ wk,
                            ushort* __restrict__ wvT, ushort* __restrict__ wpT,
                            ushort* __restrict__ xq) {
    __shared__ float tile[32][33];
    __shared__ int t_sh;
    const int bx = blockIdx.x, by = blockIdx.y;
    const int tid = threadIdx.x;

    if (bx >= 128) {                    // ---- query-row path ----
        int bw = (bx - 128) * 32 + by;
        if (tid < 32) {
            int s = mask[bw * 32 + tid];
            #pragma unroll
            for (int off = 16; off; off >>= 1) s += __shfl_xor(s, off);
            if (tid == 0) t_sh = s - 1;
        }
        __syncthreads();
        int t = t_sh;
        float4 v = ((const float4*)(x + ((size_t)bw * 32 + t) * 1024))[tid];
        ushort4 o;
        o.x = f2bf(v.x); o.y = f2bf(v.y); o.z = f2bf(v.z); o.w = f2bf(v.w);
        ((ushort4*)(xq + (size_t)bw * 1024))[tid] = o;
        return;
    }

    const int tx = tid & 31, ty = tid >> 5;    // ---- weight path ----
    const int r0 = by * 32;
    if (bx >= 96) {                      // cast: wk[r][c] = attn_w[r][1024+c]
        int c0 = (bx - 96) * 32;
        for (int i = ty; i < 32; i += 8)
            wk[(size_t)(r0 + i) * 1024 + c0 + tx] =
                f2bf(attn_w[(size_t)(r0 + i) * 3072 + 1024 + c0 + tx]);
        return;
    }
    const float* src; ushort* dst; int N, csrc0, c0;
    if (bx < 32)      { src = attn_w; dst = wqT; N = 3072; c0 = bx * 32;        csrc0 = c0; }
    else if (bx < 64) { src = attn_w; dst = wvT; N = 3072; c0 = (bx - 32) * 32; csrc0 = 2048 + c0; }
    else              { src = proj_w; dst = wpT; N = 1024; c0 = (bx - 64) * 32; csrc0 = c0; }
    for (int i = ty; i < 32; i += 8)
        tile[i][tx] = src[(size_t)(r0 + i) * N + csrc0 + tx];
    __syncthreads();
    for (int i = ty; i < 32; i += 8)
        dst[(size_t)(c0 + i) * 1024 + r0 + tx] = f2bf(tile[tx][i]);
}

// ---------- kernel 2: split-K 64-tile GEMM, M=N=1024, lda=ldb=1024 ----------
__global__ __launch_bounds__(256)
void gemm64sk_kernel(const ushort* __restrict__ A, const ushort* __restrict__ Bt,
                     float* __restrict__ Cpart) {
    __shared__ ushort As[64 * 32];
    __shared__ ushort Bs[64 * 32];

    const int bm = blockIdx.x, bn = blockIdx.y, z = blockIdx.z;
    const int kofs = z * 256;

    const int tid  = threadIdx.x;
    const int wave = tid >> 6;
    const int lane = tid & 63;
    const int wm = wave & 1, wn = wave >> 1;
    const int quad = lane >> 4, l15 = lane & 15;

    floatx4 acc[2][2] = {};

    const int srow = wave * 16 + (lane >> 2);
    const int kcol = (lane & 3) * 8;

    for (int kt = 0; kt < 256; kt += 32) {
        const ushort* gA = A  + (size_t)(bm * 64 + srow) * 1024 + kofs + kt + kcol;
        const ushort* gB = Bt + (size_t)(bn * 64 + srow) * 1024 + kofs + kt + kcol;
        ushort* lA = As + (wave * 16) * 32;
        ushort* lB = Bs + (wave * 16) * 32;
        __builtin_amdgcn_global_load_lds(GPTR(gA), LPTR(lA), 16, 0, 0);
        __builtin_amdgcn_global_load_lds(GPTR(gB), LPTR(lB), 16, 0, 0);
        __syncthreads();

        short8 af[2], bf[2];
        #pragma unroll
        for (int i = 0; i < 2; ++i)
            af[i] = *(const short8*)&As[(wm * 32 + i * 16 + l15) * 32 + quad * 8];
        #pragma unroll
        for (int j = 0; j < 2; ++j)
            bf[j] = *(const short8*)&Bs[(wn * 32 + j * 16 + l15) * 32 + quad * 8];
        #pragma unroll
        for (int i = 0; i < 2; ++i)
            #pragma unroll
            for (int j = 0; j < 2; ++j)
                acc[i][j] = __builtin_amdgcn_mfma_f32_16x16x32_bf16(af[i], bf[j], acc[i][j], 0, 0, 0);
        __syncthreads();
    }

    #pragma unroll
    for (int i = 0; i < 2; ++i) {
        #pragma unroll
        for (int j = 0; j < 2; ++j) {
            int r0 = bm * 64 + wm * 32 + i * 16 + quad * 4;
            int c  = bn * 64 + wn * 32 + j * 16 + l15;
            #pragma unroll
            for (int r = 0; r < 4; ++r)
                Cpart[(size_t)z * 1048576 + (size_t)(r0 + r) * 1024 + c] = acc[i][j][r];
        }
    }
}

// ---------- kernel 2b: combine 4 f32 partial planes ----------
template <bool OUT_BF16>
__global__ void combine4_kernel(const float* __restrict__ P, void* __restrict__ C) {
    int i = blockIdx.x * 256 + threadIdx.x;
    const float4* p = (const float4*)P;
    float4 a = p[i], b = p[i + 262144], c = p[i + 524288], d = p[i + 786432];
    float4 s;
    s.x = a.x + b.x + c.x + d.x;
    s.y = a.y + b.y + c.y + d.y;
    s.z = a.z + b.z + c.z + d.z;
    s.w = a.w + b.w + c.w + d.w;
    if (OUT_BF16) {
        ushort4 o;
        o.x = f2bf(s.x); o.y = f2bf(s.y); o.z = f2bf(s.z); o.w = f2bf(s.w);
        ((ushort4*)C)[i] = o;
    } else {
        ((float4*)C)[i] = s;
    }
}

// ---------- kernel 3: 128-tile GEMM (batched/strided) for U ----------
template <bool OUT_BF16>
__global__ __launch_bounds__(256)
void gemm128_kernel(const ushort* __restrict__ A, int lda, long sA,
                    const ushort* __restrict__ Bt, int ldb, long sB,
                    void* __restrict__ C, int ldc, long sC, int K) {
    __shared__ ushort As[128 * 32];
    __shared__ ushort Bs[128 * 32];

    const int bm = blockIdx.x, bn = blockIdx.y, z = blockIdx.z;
    A  += (size_t)z * sA;
    Bt += (size_t)z * sB;

    const int tid  = threadIdx.x;
    const int wave = tid >> 6;
    const int lane = tid & 63;
    const int wm = wave & 1, wn = wave >> 1;
    const int quad = lane >> 4, l15 = lane & 15;

    floatx4 acc[4][4] = {};

    const int arow = bm * 128 + wave * 16 + (lane >> 2);
    const int brow = bn * 128 + wave * 16 + (lane >> 2);
    const int kcol = (lane & 3) * 8;

    for (int kt = 0; kt < K; kt += 32) {
        #pragma unroll
        for (int iss = 0; iss < 2; ++iss) {
            const ushort* gA = A  + (size_t)(arow + iss * 64) * lda + kt + kcol;
            const ushort* gB = Bt + (size_t)(brow + iss * 64) * ldb + kt + kcol;
            ushort* lA = As + (iss * 64 + wave * 16) * 32;
            ushort* lB = Bs + (iss * 64 + wave * 16) * 32;
            __builtin_amdgcn_global_load_lds(GPTR(gA), LPTR(lA), 16, 0, 0);
            __builtin_amdgcn_global_load_lds(GPTR(gB), LPTR(lB), 16, 0, 0);
        }
        __syncthreads();

        short8 af[4], bf[4];
        #pragma unroll
        for (int i = 0; i < 4; ++i)
            af[i] = *(const short8*)&As[(wm * 64 + i * 16 + l15) * 32 + quad * 8];
        #pragma unroll
        for (int j = 0; j < 4; ++j)
            bf[j] = *(const short8*)&Bs[(wn * 64 + j * 16 + l15) * 32 + quad * 8];
        #pragma unroll
        for (int i = 0; i < 4; ++i)
            #pragma unroll
            for (int j = 0; j < 4; ++j)
                acc[i][j] = __builtin_amdgcn_mfma_f32_16x16x32_bf16(af[i], bf[j], acc[i][j], 0, 0, 0);
        __syncthreads();
    }

    #pragma unroll
    for (int i = 0; i < 4; ++i) {
        #pragma unroll
        for (int j = 0; j < 4; ++j) {
            int r0 = bm * 128 + wm * 64 + i * 16 + quad * 4;
            int c  = bn * 128 + wn * 64 + j * 16 + l15;
            #pragma unroll
            for (int r = 0; r < 4; ++r) {
                float v = acc[i][j][r];
                size_t idx = (size_t)z * sC + (size_t)(r0 + r) * ldc + c;
                if (OUT_BF16) ((ushort*)C)[idx] = f2bf(v);
                else          ((float*) C)[idx] = v;
            }
        }
    }
}

// ---------- kernel 3b: 64-tile GEMM (batched/strided), optional pos-add ----------
template <bool OUT_BF16, bool ADD_POS>
__global__ __launch_bounds__(256)
void gemm64_kernel(const ushort* __restrict__ A, int lda, long sA,
                   const ushort* __restrict__ Bt, int ldb, long sB,
                   void* __restrict__ C, int ldc, int cColPerZ, int K,
                   const float* __restrict__ pos) {
    __shared__ ushort As[64 * 32];
    __shared__ ushort Bs[64 * 32];

    const int bm = blockIdx.x, bn = blockIdx.y, z = blockIdx.z;
    A  += (size_t)z * sA;
    Bt += (size_t)z * sB;

    const int tid  = threadIdx.x;
    const int wave = tid >> 6;
    const int lane = tid & 63;
    const int wm = wave & 1, wn = wave >> 1;
    const int quad = lane >> 4, l15 = lane & 15;

    floatx4 acc[2][2] = {};

    const int srow = wave * 16 + (lane >> 2);
    const int kcol = (lane & 3) * 8;

    for (int kt = 0; kt < K; kt += 32) {
        const ushort* gA = A  + (size_t)(bm * 64 + srow) * lda + kt + kcol;
        const ushort* gB = Bt + (size_t)(bn * 64 + srow) * ldb + kt + kcol;
        ushort* lA = As + (wave * 16) * 32;
        ushort* lB = Bs + (wave * 16) * 32;
        __builtin_amdgcn_global_load_lds(GPTR(gA), LPTR(lA), 16, 0, 0);
        __builtin_amdgcn_global_load_lds(GPTR(gB), LPTR(lB), 16, 0, 0);
        __syncthreads();

        short8 af[2], bf[2];
        #pragma unroll
        for (int i = 0; i < 2; ++i)
            af[i] = *(const short8*)&As[(wm * 32 + i * 16 + l15) * 32 + quad * 8];
        #pragma unroll
        for (int j = 0; j < 2; ++j)
            bf[j] = *(const short8*)&Bs[(wn * 32 + j * 16 + l15) * 32 + quad * 8];
        #pragma unroll
        for (int i = 0; i < 2; ++i)
            #pragma unroll
            for (int j = 0; j < 2; ++j)
                acc[i][j] = __builtin_amdgcn_mfma_f32_16x16x32_bf16(af[i], bf[j], acc[i][j], 0, 0, 0);
        __syncthreads();
    }

    #pragma unroll
    for (int i = 0; i < 2; ++i) {
        #pragma unroll
        for (int j = 0; j < 2; ++j) {
            int r0 = bm * 64 + wm * 32 + i * 16 + quad * 4;
            int cc = z * cColPerZ + bn * 64 + wn * 32 + j * 16 + l15;
            #pragma unroll
            for (int r = 0; r < 4; ++r) {
                float v = acc[i][j][r];
                if (ADD_POS) v += pos[(size_t)((r0 + r) & 255) * 1024 + cc];
                size_t idx = (size_t)(r0 + r) * ldc + cc;
                if (OUT_BF16) ((ushort*)C)[idx] = f2bf(v);
                else          ((float*) C)[idx] = v;
            }
        }
    }
}

// ---------- kernel 4: fused scores -> softmax -> Z, chunked staging (~32 KB LDS) ----------
// S phase: 256-col chunks of X (rows 0..t) and U staged in LDS; all 4 waves MFMA
// (2 m-tiles x 2 k-halves, halves reduced via LDS). Z phase: x read fp32 from
// global (L2/L3-warm), P broadcast from LDS.
__global__ __launch_bounds__(256)
void attn2_kernel(const float* __restrict__ x, const int* __restrict__ mask,
                  const ushort* __restrict__ U, ushort* __restrict__ Z) {
    __shared__ ushort Xs[32 * 264];     // 16.5 KB chunk of X (bf16, +8 pad)
    __shared__ ushort Us[16 * 264];     // 8.25 KB chunk of U
    __shared__ float  Sp[2][16][16];    // k-half partials
    __shared__ float  Ss[16 * 36];      // scores [h][j]
    __shared__ float  Ps[32 * 16];      // probs [j][h]
    __shared__ int    t_sh;

    const int bw = blockIdx.x;
    const int tid = threadIdx.x;
    const int wave = tid >> 6, lane = tid & 63;
    const int quad = lane >> 4, l15 = lane & 15;

    if (tid < 32) {
        int s = mask[bw * 32 + tid];
        #pragma unroll
        for (int off = 16; off; off >>= 1) s += __shfl_xor(s, off);
        if (tid == 0) t_sh = s - 1;
    }
    __syncthreads();
    const int t = t_sh;

    const int m  = wave & 1;            // m-tile (rows m*16..m*16+15)
    const int kh = wave >> 1;           // k-half within chunk
    floatx4 acc = {0.f, 0.f, 0.f, 0.f};

    const float4* xsrc = (const float4*)(x + (size_t)bw * 32768);
    const ushort* ubase = U + (size_t)bw * 16384;

    for (int c = 0; c < 4; ++c) {       // 4 chunks of 256 cols
        int nx4 = (t + 1) * 64;
        for (int i = tid; i < nx4; i += 256) {
            int j = i >> 6, c4 = i & 63;
            float4 v = xsrc[j * 256 + c * 64 + c4];
            ushort4 o; o.x = f2bf(v.x); o.y = f2bf(v.y); o.z = f2bf(v.z); o.w = f2bf(v.w);
            *(ushort4*)&Xs[j * 264 + c4 * 4] = o;
        }
        for (int i = tid; i < 16 * 32; i += 256) {
            int h = i >> 5, c8 = i & 31;
            *(short8*)&Us[h * 264 + c8 * 8] = *(const short8*)&ubase[h * 1024 + c * 256 + c8 * 8];
        }
        __syncthreads();
        #pragma unroll
        for (int ks = 0; ks < 4; ++ks) {
            short8 a = *(const short8*)&Xs[(m * 16 + l15) * 264 + kh * 128 + ks * 32 + quad * 8];
            short8 b = *(const short8*)&Us[l15 * 264 + kh * 128 + ks * 32 + quad * 8];
            acc = __builtin_amdgcn_mfma_f32_16x16x32_bf16(a, b, acc, 0, 0, 0);
        }
        __syncthreads();
    }

    // reduce the two k-halves
    if (kh == 1) {
        #pragma unroll
        for (int r = 0; r < 4; ++r) Sp[m][quad * 4 + r][l15] = acc[r];
    }
    __syncthreads();
    if (kh == 0) {
        #pragma unroll
        for (int r = 0; r < 4; ++r)
            Ss[l15 * 36 + m * 16 + quad * 4 + r] =
                (acc[r] + Sp[m][quad * 4 + r][l15]) * 0.125f;
    }
    __syncthreads();

    // softmax per head (wave 0): h = l15, quad owns j = quad*8..quad*8+7
    if (wave == 0) {
        float s[8]; float mx = -1e30f;
        #pragma unroll
        for (int r = 0; r < 8; ++r) {
            int j = quad * 8 + r;
            float v = Ss[l15 * 36 + j];
            v = (j <= t) ? v : -1e30f;
            s[r] = v; mx = fmaxf(mx, v);
        }
        mx = fmaxf(mx, __shfl_xor(mx, 16));
        mx = fmaxf(mx, __shfl_xor(mx, 32));
        float l = 0.f;
        #pragma unroll
        for (int r = 0; r < 8; ++r) { s[r] = __expf(s[r] - mx); l += s[r]; }
        l += __shfl_xor(l, 16);
        l += __shfl_xor(l, 32);
        float inv = 1.f / l;
        #pragma unroll
        for (int r = 0; r < 8; ++r)
            Ps[(quad * 8 + r) * 16 + l15] = s[r] * inv;
    }
    __syncthreads();

    // Z[h][e] = sum_j P[j][h] * x[j][e]; thread owns 4 consecutive e (fp32 x from global)
    float z[16][4];
    #pragma unroll
    for (int h = 0; h < 16; ++h)
        #pragma unroll
        for (int cc = 0; cc < 4; ++cc) z[h][cc] = 0.f;
    for (int j = 0; j <= t; ++j) {
        float4 p0 = *(const float4*)&Ps[j * 16 + 0];
        float4 p1 = *(const float4*)&Ps[j * 16 + 4];
        float4 p2 = *(const float4*)&Ps[j * 16 + 8];
        float4 p3 = *(const float4*)&Ps[j * 16 + 12];
        float pr[16] = {p0.x, p0.y, p0.z, p0.w, p1.x, p1.y, p1.z, p1.w,
                        p2.x, p2.y, p2.z, p2.w, p3.x, p3.y, p3.z, p3.w};
        float4 xv = xsrc[j * 256 + tid];
        float xf[4] = {xv.x, xv.y, xv.z, xv.w};
        #pragma unroll
        for (int h = 0; h < 16; ++h)
            #pragma unroll
            for (int cc = 0; cc < 4; ++cc)
                z[h][cc] += pr[h] * xf[cc];
    }
    const int e0 = tid * 4;
    #pragma unroll
    for (int h = 0; h < 16; ++h) {
        ushort4 o;
        o.x = f2bf(z[h][0]); o.y = f2bf(z[h][1]);
        o.z = f2bf(z[h][2]); o.w = f2bf(z[h][3]);
        *(ushort4*)&Z[(size_t)bw * 16384 + h * 1024 + e0] = o;
    }
}

// ---------- launch ----------
extern "C" void kernel_launch(void* const* d_in, const int* in_sizes, int n_in,
                              void* d_out, int out_size, void* d_ws, size_t ws_size,
                              hipStream_t stream) {
    const float* x        = (const float*)d_in[0];   // (4,256,32,1024)
    const int*   mask     = (const int*)  d_in[1];   // (4,256,32)
    const float* pos_emb  = (const float*)d_in[2];   // (256,1024)
    const float* attn_w   = (const float*)d_in[3];   // (1024,3072)
    const float* proj_w   = (const float*)d_in[4];   // (1024,1024)
    float*       out      = (float*)d_out;           // (1024,1024)

    const long MB2 = 1048576;

    char* ws = (char*)d_ws;
    size_t off = 0;
    ushort* U_bf  = (ushort*)(ws + off); off += (size_t)16 * MB2 * 2;    // U[bw][h][e]
    ushort* Z_bf  = (ushort*)(ws + off); off += (size_t)16 * MB2 * 2;    // Z[bw][h][e]
    float*  qpart = (float*) (ws + off); off += (size_t)4 * MB2 * 4;     // split-K partials
    float*  opart = (float*) (ws + off); off += (size_t)4 * MB2 * 4;
    ushort* wqT   = (ushort*)(ws + off); off += MB2 * 2;
    ushort* wk    = (ushort*)(ws + off); off += MB2 * 2;
    ushort* wvT   = (ushort*)(ws + off); off += MB2 * 2;
    ushort* wpT   = (ushort*)(ws + off); off += MB2 * 2;
    ushort* xq_bf = (ushort*)(ws + off); off += MB2 * 2;
    ushort* q_bf  = (ushort*)(ws + off); off += MB2 * 2;
    ushort* y_bf  = (ushort*)(ws + off); off += MB2 * 2;

    // 1. weight prep + query rows (one dispatch)
    prep_kernel<<<dim3(160, 32), 256, 0, stream>>>(attn_w, proj_w, x, mask,
                                                   wqT, wk, wvT, wpT, xq_bf);

    // 2. Q = Xq @ Wq  (1024^3) via split-K=4, combine -> bf16
    gemm64sk_kernel<<<dim3(16, 16, 4), 256, 0, stream>>>(xq_bf, wqT, qpart);
    combine4_kernel<true><<<1024, 256, 0, stream>>>(qpart, (void*)q_bf);

    // 3. U[bw][h][e] = Q^h @ (Wk^h)^T  — batched 16 x (1024x1024x64)
    gemm128_kernel<true><<<dim3(8, 8, 16), 256, 0, stream>>>(
        q_bf, 1024, 64, wk, 1024, 64, (void*)U_bf, 16384, 1024, 64);

    // 4. fused scores -> softmax -> Z per window
    attn2_kernel<<<1024, 256, 0, stream>>>(x, mask, U_bf, Z_bf);

    // 5. y = Z^h @ Wv^h + pos  — batched 16 x (1024x64x1024), bf16 out
    gemm64_kernel<true, true><<<dim3(16, 1, 16), 256, 0, stream>>>(
        Z_bf, 16384, 1024, wvT, 1024, 65536, (void*)y_bf, 1024, 64, 1024, pos_emb);

    // 6. out = y @ Wproj  (1024^3) via split-K=4, combine -> f32
    gemm64sk_kernel<<<dim3(16, 16, 4), 256, 0, stream>>>(y_bf, wpT, opart);
    combine4_kernel<false><<<1024, 256, 0, stream>>>(opart, (void*)out);
}